// Round 13
// baseline (164.448 us; speedup 1.0000x reference)
//
#include <hip/hip_runtime.h>
#include <hip/hip_fp16.h>

#define NN 50000
#define NE 800000
#define D  128
#define NB 391                 // node buckets of 128
#define NS 256                 // sorter blocks
#define EPS 3125               // edges per sorter (NS*EPS == NE)
#define SN (NB * NS)           // 100096 scan elements
#define SCB 1024
#define NSB ((SN + SCB - 1) / SCB)   // 98
#define NCHUNK 8               // feature chunks (16 cols each)

// ---- main-path ws layout (bytes) ----
#define OFF_SLAB 0             // int2[2E]      12,800,000
#define OFF_XW   0             // ushort[NN*D]  12,800,000 (chunk-major; aliases dead slab)
#define OFF_CSR4 12800000      // uint[2E]       6,400,000
#define OFF_HIST 19200000      // int[SN]          400,384
#define OFF_BASE 19600384      // int[SN]          400,384
#define OFF_BSUM 20000768      // int[NSB]             512
#define OFF_ROW  20001280      // int[NN+1]        200,004
#define NEED_A   20201284

// ---- fallback ws layout ----
#define OFF_CNT  0
#define OFF_ROWF 200704
#define OFF_CUR  401408
#define OFF_CSR8 602112

__device__ __forceinline__ float bf_lo(unsigned int v) { return __uint_as_float(v << 16); }
__device__ __forceinline__ float bf_hi(unsigned int v) { return __uint_as_float(v & 0xffff0000u); }
__device__ __forceinline__ float wdec(unsigned int v) {
    return __half2float(__ushort_as_half((unsigned short)(v >> 16)));
}
__device__ __forceinline__ unsigned short bf16rne(float f) {
    unsigned int b = __float_as_uint(f);
    return (unsigned short)((b + 0x7fffu + ((b >> 16) & 1u)) >> 16);
}

// K1: per-sorter histogram over 391 buckets (LDS), b-major output
__global__ __launch_bounds__(256) void gc_shist(
    const int2* __restrict__ edges, int* __restrict__ histT)
{
    __shared__ int h[NB];
    const int s = blockIdx.x;
    for (int i = threadIdx.x; i < NB; i += 256) h[i] = 0;
    __syncthreads();
    const int e0 = s * EPS;
    for (int i = threadIdx.x; i < EPS; i += 256) {
        int2 p = edges[e0 + i];
        atomicAdd(&h[p.y >> 7], 1);
        atomicAdd(&h[p.x >> 7], 1);
    }
    __syncthreads();
    for (int b = threadIdx.x; b < NB; b += 256) histT[b * NS + s] = h[b];
}

// K2a/b/c: hierarchical exclusive scan over SN elements
__global__ __launch_bounds__(256) void gc_scanA(
    const int* __restrict__ in, int* __restrict__ bsum)
{
    __shared__ int red[256];
    int base = blockIdx.x * SCB;
    int s = 0;
    for (int i = threadIdx.x; i < SCB; i += 256) {
        int idx = base + i;
        s += (idx < SN) ? in[idx] : 0;
    }
    red[threadIdx.x] = s;
    __syncthreads();
    for (int off = 128; off > 0; off >>= 1) {
        if (threadIdx.x < off) red[threadIdx.x] += red[threadIdx.x + off];
        __syncthreads();
    }
    if (threadIdx.x == 0) bsum[blockIdx.x] = red[0];
}

__global__ __launch_bounds__(1024) void gc_scanB(int* __restrict__ bsum)
{
    __shared__ int part[1024];
    int t = threadIdx.x;
    int v = (t < NSB) ? bsum[t] : 0;
    part[t] = v;
    __syncthreads();
    for (int off = 1; off < 1024; off <<= 1) {
        int x = (t >= off) ? part[t - off] : 0;
        __syncthreads();
        part[t] += x;
        __syncthreads();
    }
    if (t < NSB) bsum[t] = part[t] - v;
}

__global__ __launch_bounds__(256) void gc_scanC(
    const int* __restrict__ in, const int* __restrict__ bsum,
    int* __restrict__ baseT)
{
    __shared__ int part[256];
    int base = blockIdx.x * SCB;
    int idx0 = base + threadIdx.x * 4;
    int4 v = make_int4(0, 0, 0, 0);
    if (idx0 + 3 < SN) v = *reinterpret_cast<const int4*>(in + idx0);
    int s = v.x + v.y + v.z + v.w;
    part[threadIdx.x] = s;
    __syncthreads();
    for (int off = 1; off < 256; off <<= 1) {
        int x = (threadIdx.x >= off) ? part[threadIdx.x - off] : 0;
        __syncthreads();
        part[threadIdx.x] += x;
        __syncthreads();
    }
    int run = bsum[blockIdx.x] + part[threadIdx.x] - s;
    if (idx0 + 3 < SN)
        *reinterpret_cast<int4*>(baseT + idx0) =
            make_int4(run, run + v.x, run + v.x + v.y, run + v.x + v.y + v.z);
}

// K3: scatter entries into per-(sorter,bucket) contiguous chunks
__global__ __launch_bounds__(256) void gc_sscat(
    const int2* __restrict__ edges, const float* __restrict__ wts,
    const int* __restrict__ baseT, int2* __restrict__ slab)
{
    __shared__ int cur[NB];
    const int s = blockIdx.x;
    for (int b = threadIdx.x; b < NB; b += 256) cur[b] = baseT[b * NS + s];
    __syncthreads();
    const int e0 = s * EPS;
    for (int i = threadIdx.x; i < EPS; i += 256) {
        int2 p = edges[e0 + i];
        int wb = __float_as_int(wts[e0 + i]);
        int b = p.y >> 7;
        int pos = atomicAdd(&cur[b], 1);
        slab[pos] = make_int2(p.x | ((p.y & 127) << 16), wb);
        b = p.x >> 7;
        pos = atomicAdd(&cur[b], 1);
        slab[pos] = make_int2(p.y | ((p.x & 127) << 16), wb);
    }
}

// K4: per-bucket CSR build from the contiguous bucket region
__global__ __launch_bounds__(256) void gc_csr(
    const int* __restrict__ baseT, const int2* __restrict__ slab,
    int* __restrict__ row_start, unsigned int* __restrict__ csr4)
{
    __shared__ int ncnt[128], ncur[128], part[128];
    const int tid = threadIdx.x;
    const int b = blockIdx.x;
    const int start = baseT[b * NS];
    const int end = (b == NB - 1) ? (2 * NE) : baseT[(b + 1) * NS];

    if (tid < 128) ncnt[tid] = 0;
    __syncthreads();

    for (int j = start + tid; j < end; j += 256)
        atomicAdd(&ncnt[(slab[j].x >> 16) & 127], 1);
    __syncthreads();

    if (tid < 128) part[tid] = ncnt[tid];
    __syncthreads();
    for (int off = 1; off < 128; off <<= 1) {
        int v = 0;
        if (tid < 128 && tid >= off) v = part[tid - off];
        __syncthreads();
        if (tid < 128) part[tid] += v;
        __syncthreads();
    }
    if (tid < 128) {
        int st = start + part[tid] - ncnt[tid];
        int n = b * 128 + tid;
        if (n < NN) row_start[n] = st;
        ncur[tid] = st;
    }
    if (b == 0 && tid == 0) row_start[NN] = 2 * NE;
    __syncthreads();

    for (int j = start + tid; j < end; j += 256) {
        int2 en = slab[j];
        int dl = (en.x >> 16) & 127;
        unsigned int hb =
            (unsigned int)__half_as_ushort(__float2half_rn(__int_as_float(en.y))) << 16;
        int pos = atomicAdd(&ncur[dl], 1);
        csr4[pos] = (unsigned int)(en.x & 0xffff) | hb;
    }
}

// K5: XW = X @ W, bf16 RNE, chunk-major output XWc[chunk][node][16 cols].
// 4x4 register blocking: 8 ds_read_b128 per 64 FMA (vs 9 b32 per 8 FMA).
// Block = 256 threads: tr=tid>>5 (8 row-groups x 4 rows), tc=tid&31 (4 cols).
__global__ __launch_bounds__(256) void gc_gemm_rb(
    const float* __restrict__ src, unsigned short* __restrict__ dst,
    const float* __restrict__ Wm)
{
    __shared__ float Ws[D * D];        // 64 KB
    __shared__ float As[32 * D];       // 16 KB
    const int tid = threadIdx.x;
    const int tr  = tid >> 5;
    const int tc  = tid & 31;
    const int rbase = blockIdx.x * 32;

    const float4* W4  = reinterpret_cast<const float4*>(Wm);
    float4*       Ws4 = reinterpret_cast<float4*>(Ws);
    #pragma unroll
    for (int i = 0; i < 16; ++i) Ws4[tid + i * 256] = W4[tid + i * 256];

    const float4* X4  = reinterpret_cast<const float4*>(src);
    float4*       A4l = reinterpret_cast<float4*>(As);
    #pragma unroll
    for (int i = 0; i < 4; ++i) {
        int f = tid + i * 256;             // 1024 float4 = 32 rows x 32 f4
        int r = f >> 5, q = f & 31;
        int grow = rbase + r;
        A4l[f] = (grow < NN) ? X4[(size_t)grow * 32 + q]
                             : make_float4(0.f, 0.f, 0.f, 0.f);
    }
    __syncthreads();

    float4 acc[4];
    #pragma unroll
    for (int i = 0; i < 4; ++i) acc[i] = make_float4(0.f, 0.f, 0.f, 0.f);

    for (int k4 = 0; k4 < 32; ++k4) {
        float4 w0 = Ws4[(4 * k4 + 0) * 32 + tc];
        float4 w1 = Ws4[(4 * k4 + 1) * 32 + tc];
        float4 w2 = Ws4[(4 * k4 + 2) * 32 + tc];
        float4 w3 = Ws4[(4 * k4 + 3) * 32 + tc];
        #pragma unroll
        for (int i = 0; i < 4; ++i) {
            float4 a = A4l[(tr * 4 + i) * 32 + k4];
            acc[i].x = fmaf(a.x, w0.x, acc[i].x); acc[i].y = fmaf(a.x, w0.y, acc[i].y);
            acc[i].z = fmaf(a.x, w0.z, acc[i].z); acc[i].w = fmaf(a.x, w0.w, acc[i].w);
            acc[i].x = fmaf(a.y, w1.x, acc[i].x); acc[i].y = fmaf(a.y, w1.y, acc[i].y);
            acc[i].z = fmaf(a.y, w1.z, acc[i].z); acc[i].w = fmaf(a.y, w1.w, acc[i].w);
            acc[i].x = fmaf(a.z, w2.x, acc[i].x); acc[i].y = fmaf(a.z, w2.y, acc[i].y);
            acc[i].z = fmaf(a.z, w2.z, acc[i].z); acc[i].w = fmaf(a.z, w2.w, acc[i].w);
            acc[i].x = fmaf(a.w, w3.x, acc[i].x); acc[i].y = fmaf(a.w, w3.y, acc[i].y);
            acc[i].z = fmaf(a.w, w3.z, acc[i].z); acc[i].w = fmaf(a.w, w3.w, acc[i].w);
        }
    }

    const int c0 = tc * 4;                 // c0 % 16 in {0,4,8,12}
    const size_t chunkBase = (size_t)(c0 >> 4) * (NN * 16) + (c0 & 15);
    #pragma unroll
    for (int i = 0; i < 4; ++i) {
        int row = rbase + tr * 4 + i;
        if (row < NN) {
            ushort4 o;
            o.x = bf16rne(acc[i].x); o.y = bf16rne(acc[i].y);
            o.z = bf16rne(acc[i].z); o.w = bf16rne(acc[i].w);
            *reinterpret_cast<ushort4*>(dst + chunkBase + (size_t)row * 16) = o;
        }
    }
}

// K6: chunked gather. Block b: chunk g=b&7 (XCD-resident 1.6MB slab), nodes
// (b>>3)*32..+31. 8 lanes per node, lane c owns 2 cols (one packed uint).
__global__ __launch_bounds__(256) void gc_gather_c(
    const int* __restrict__ row_start, const unsigned int* __restrict__ csr4,
    const unsigned int* __restrict__ XWc, float* __restrict__ out)
{
    const int g    = blockIdx.x & (NCHUNK - 1);
    const int node = (blockIdx.x >> 3) * 32 + (threadIdx.x >> 3);
    const int c    = threadIdx.x & 7;
    if (node >= NN) return;

    const unsigned int* slabp = XWc + (size_t)g * (NN * 8) + c;
    int j   = row_start[node];
    int end = row_start[node + 1];
    float ax = 0.f, ay = 0.f, dw = 0.f;
    for (; j + 2 <= end; j += 2) {
        unsigned int e0 = csr4[j], e1 = csr4[j + 1];
        unsigned int v0 = slabp[(size_t)(e0 & 0xffffu) * 8];
        unsigned int v1 = slabp[(size_t)(e1 & 0xffffu) * 8];
        float w0 = wdec(e0), w1 = wdec(e1);
        ax = fmaf(w0, bf_lo(v0), ax); ay = fmaf(w0, bf_hi(v0), ay);
        ax = fmaf(w1, bf_lo(v1), ax); ay = fmaf(w1, bf_hi(v1), ay);
        dw += w0 + w1;
    }
    if (j < end) {
        unsigned int e0 = csr4[j];
        unsigned int v0 = slabp[(size_t)(e0 & 0xffffu) * 8];
        float w0 = wdec(e0);
        ax = fmaf(w0, bf_lo(v0), ax); ay = fmaf(w0, bf_hi(v0), ay);
        dw += w0;
    }
    float inv = dw > 0.f ? 1.f / dw : 0.f;
    float2 r; r.x = ax * inv; r.y = ay * inv;
    *reinterpret_cast<float2*>(out + (size_t)node * D + g * 16 + c * 2) = r;
}

// ======================= fallback path (fp32, small ws) ====================
__global__ __launch_bounds__(256) void gc_hist(
    const int2* __restrict__ edges, int* __restrict__ counts)
{
    int e = blockIdx.x * 256 + threadIdx.x;
    if (e >= NE) return;
    int2 p = edges[e];
    atomicAdd(counts + p.x, 1);
    atomicAdd(counts + p.y, 1);
}

__global__ __launch_bounds__(1024) void gc_scan(
    const int* __restrict__ counts, int* __restrict__ row_start,
    int* __restrict__ cursor)
{
    const int CHUNK = (NN + 1023) / 1024;
    __shared__ int part[1024];
    int t = threadIdx.x;
    int lo = t * CHUNK, hi = min(lo + CHUNK, NN);
    int s = 0;
    for (int i = lo; i < hi; ++i) s += counts[i];
    part[t] = s;
    __syncthreads();
    for (int off = 1; off < 1024; off <<= 1) {
        int v = (t >= off) ? part[t - off] : 0;
        __syncthreads();
        part[t] += v;
        __syncthreads();
    }
    int run = part[t] - s;
    for (int i = lo; i < hi; ++i) {
        int c = counts[i];
        row_start[i] = run;
        cursor[i]    = run;
        run += c;
    }
    if (t == 1023) row_start[NN] = part[1023];
}

__global__ __launch_bounds__(256) void gc_fill8(
    const int2* __restrict__ edges, const float* __restrict__ wts,
    int* __restrict__ cursor, int2* __restrict__ csr)
{
    int e = blockIdx.x * 256 + threadIdx.x;
    if (e >= NE) return;
    int2 p = edges[e];
    int wb = __float_as_int(wts[e]);
    int pos = atomicAdd(cursor + p.y, 1);
    csr[pos] = make_int2(p.x, wb);
    pos = atomicAdd(cursor + p.x, 1);
    csr[pos] = make_int2(p.y, wb);
}

__global__ __launch_bounds__(256) void gc_gather_f32(
    const int* __restrict__ row_start, const int2* __restrict__ csr,
    const float* __restrict__ F, float* __restrict__ out)
{
    int wid  = (blockIdx.x * 256 + threadIdx.x) >> 6;
    int lane = threadIdx.x & 63;
    if (wid >= NN) return;
    int j   = row_start[wid];
    int end = row_start[wid + 1];
    const float2* F2 = reinterpret_cast<const float2*>(F);
    float ax = 0.f, ay = 0.f, dw = 0.f;
    for (; j < end; ++j) {
        int2  cw = csr[j];
        float w  = __int_as_float(cw.y);
        float2 xv = F2[(size_t)cw.x * 64 + lane];
        ax = fmaf(w, xv.x, ax);
        ay = fmaf(w, xv.y, ay);
        dw += w;
    }
    float inv = dw > 0.f ? 1.f / dw : 0.f;
    float2 r; r.x = ax * inv; r.y = ay * inv;
    reinterpret_cast<float2*>(out)[(size_t)wid * 64 + lane] = r;
}

__global__ __launch_bounds__(256) void gc_gemm_f32(
    const float* __restrict__ src, float* __restrict__ dst,
    const float* __restrict__ Wm)
{
    __shared__ float Ws[D * D];
    __shared__ float axs[16 * D];
    const int tid = threadIdx.x;
    const int col = tid & 127;
    const int ty  = tid >> 7;
    const int rbase = blockIdx.x * 16;

    const float4* W4  = reinterpret_cast<const float4*>(Wm);
    float4*       Ws4 = reinterpret_cast<float4*>(Ws);
    #pragma unroll
    for (int i = 0; i < 16; ++i) Ws4[tid + i * 256] = W4[tid + i * 256];

    const float4* A4   = reinterpret_cast<const float4*>(src + (size_t)rbase * D);
    float4*       axs4 = reinterpret_cast<float4*>(axs);
    #pragma unroll
    for (int i = 0; i < 2; ++i) axs4[tid + i * 256] = A4[tid + i * 256];
    __syncthreads();

    float acc[8];
    #pragma unroll
    for (int i = 0; i < 8; ++i) acc[i] = 0.f;

    for (int k = 0; k < D; ++k) {
        float wv = Ws[k * D + col];
        #pragma unroll
        for (int i = 0; i < 8; ++i)
            acc[i] = fmaf(axs[(ty * 8 + i) * D + k], wv, acc[i]);
    }

    #pragma unroll
    for (int i = 0; i < 8; ++i)
        dst[(size_t)(rbase + ty * 8 + i) * D + col] = acc[i];
}

extern "C" void kernel_launch(void* const* d_in, const int* in_sizes, int n_in,
                              void* d_out, int out_size, void* d_ws, size_t ws_size,
                              hipStream_t stream) {
    const float* X     = (const float*)d_in[0];
    const int2*  edges = (const int2*)d_in[1];
    const float* wts   = (const float*)d_in[2];
    const float* Wm    = (const float*)d_in[3];
    float* out = (float*)d_out;
    char*  ws  = (char*)d_ws;

    const int eblocks = (NE + 255) / 256;

    if (ws_size >= NEED_A) {
        int2* slab  = (int2*)(ws + OFF_SLAB);
        unsigned int* csr4 = (unsigned int*)(ws + OFF_CSR4);
        int*  histT = (int*)(ws + OFF_HIST);
        int*  baseT = (int*)(ws + OFF_BASE);
        int*  bsum  = (int*)(ws + OFF_BSUM);
        int*  row   = (int*)(ws + OFF_ROW);
        unsigned short* xwc = (unsigned short*)(ws + OFF_XW);  // aliases dead slab

        gc_shist<<<NS, 256, 0, stream>>>(edges, histT);
        gc_scanA<<<NSB, 256, 0, stream>>>(histT, bsum);
        gc_scanB<<<1, 1024, 0, stream>>>(bsum);
        gc_scanC<<<NSB, 256, 0, stream>>>(histT, bsum, baseT);
        gc_sscat<<<NS, 256, 0, stream>>>(edges, wts, baseT, slab);
        gc_csr<<<NB, 256, 0, stream>>>(baseT, slab, row, csr4);
        gc_gemm_rb<<<(NN + 31) / 32, 256, 0, stream>>>(X, xwc, Wm);  // overwrites slab
        gc_gather_c<<<((NN + 31) / 32) * NCHUNK, 256, 0, stream>>>(
            row, csr4, (const unsigned int*)xwc, out);
    } else {
        int*  counts    = (int*) (ws + OFF_CNT);
        int*  row_start = (int*) (ws + OFF_ROWF);
        int*  cursor    = (int*) (ws + OFF_CUR);
        int2* csr       = (int2*)(ws + OFF_CSR8);

        hipMemsetAsync(counts, 0, NN * sizeof(int), stream);
        gc_hist<<<eblocks, 256, 0, stream>>>(edges, counts);
        gc_scan<<<1, 1024, 0, stream>>>(counts, row_start, cursor);
        gc_fill8<<<eblocks, 256, 0, stream>>>(edges, wts, cursor, csr);
        gc_gather_f32<<<(NN * 64 + 255) / 256, 256, 0, stream>>>(row_start, csr, X, out);
        gc_gemm_f32<<<NN / 16, 256, 0, stream>>>(out, out, Wm);
    }
}

// Round 14
// 130.276 us; speedup vs baseline: 1.2623x; 1.2623x over previous
//
#include <hip/hip_runtime.h>
#include <hip/hip_fp16.h>

#define NN 50000
#define NE 800000
#define D  128
#define NB 391                 // node buckets of 128
#define NS 256                 // sorter blocks
#define EPS 3125               // edges per sorter (NS*EPS == NE)
#define SN (NB * NS)           // 100096 scan elements
#define SCB 1024
#define NSB ((SN + SCB - 1) / SCB)   // 98

// ---- main-path ws layout (bytes) ----
#define OFF_SLAB 0             // int2[2E]      12,800,000
#define OFF_XW   0             // ushort[NN*D]  12,800,000 (row-major; aliases dead slab)
#define OFF_CSR4 12800000      // uint[2E]       6,400,000
#define OFF_HIST 19200000      // int[SN]          400,384
#define OFF_BASE 19600384      // int[SN]          400,384
#define OFF_BSUM 20000768      // int[NSB]             512
#define OFF_ROW  20001280      // int[NN+1]        200,004
#define NEED_A   20201284

// ---- fallback ws layout ----
#define OFF_CNT  0
#define OFF_ROWF 200704
#define OFF_CUR  401408
#define OFF_CSR8 602112

__device__ __forceinline__ float bf_lo(unsigned int v) { return __uint_as_float(v << 16); }
__device__ __forceinline__ float bf_hi(unsigned int v) { return __uint_as_float(v & 0xffff0000u); }
__device__ __forceinline__ float wdec(unsigned int v) {
    return __half2float(__ushort_as_half((unsigned short)(v >> 16)));
}
__device__ __forceinline__ unsigned short bf16rne(float f) {
    unsigned int b = __float_as_uint(f);
    return (unsigned short)((b + 0x7fffu + ((b >> 16) & 1u)) >> 16);
}

// K1: per-sorter histogram over 391 buckets (LDS), b-major output
__global__ __launch_bounds__(256) void gc_shist(
    const int2* __restrict__ edges, int* __restrict__ histT)
{
    __shared__ int h[NB];
    const int s = blockIdx.x;
    for (int i = threadIdx.x; i < NB; i += 256) h[i] = 0;
    __syncthreads();
    const int e0 = s * EPS;
    for (int i = threadIdx.x; i < EPS; i += 256) {
        int2 p = edges[e0 + i];
        atomicAdd(&h[p.y >> 7], 1);
        atomicAdd(&h[p.x >> 7], 1);
    }
    __syncthreads();
    for (int b = threadIdx.x; b < NB; b += 256) histT[b * NS + s] = h[b];
}

// K2a/b/c: hierarchical exclusive scan over SN elements
__global__ __launch_bounds__(256) void gc_scanA(
    const int* __restrict__ in, int* __restrict__ bsum)
{
    __shared__ int red[256];
    int base = blockIdx.x * SCB;
    int s = 0;
    for (int i = threadIdx.x; i < SCB; i += 256) {
        int idx = base + i;
        s += (idx < SN) ? in[idx] : 0;
    }
    red[threadIdx.x] = s;
    __syncthreads();
    for (int off = 128; off > 0; off >>= 1) {
        if (threadIdx.x < off) red[threadIdx.x] += red[threadIdx.x + off];
        __syncthreads();
    }
    if (threadIdx.x == 0) bsum[blockIdx.x] = red[0];
}

__global__ __launch_bounds__(1024) void gc_scanB(int* __restrict__ bsum)
{
    __shared__ int part[1024];
    int t = threadIdx.x;
    int v = (t < NSB) ? bsum[t] : 0;
    part[t] = v;
    __syncthreads();
    for (int off = 1; off < 1024; off <<= 1) {
        int x = (t >= off) ? part[t - off] : 0;
        __syncthreads();
        part[t] += x;
        __syncthreads();
    }
    if (t < NSB) bsum[t] = part[t] - v;
}

__global__ __launch_bounds__(256) void gc_scanC(
    const int* __restrict__ in, const int* __restrict__ bsum,
    int* __restrict__ baseT)
{
    __shared__ int part[256];
    int base = blockIdx.x * SCB;
    int idx0 = base + threadIdx.x * 4;
    int4 v = make_int4(0, 0, 0, 0);
    if (idx0 + 3 < SN) v = *reinterpret_cast<const int4*>(in + idx0);
    int s = v.x + v.y + v.z + v.w;
    part[threadIdx.x] = s;
    __syncthreads();
    for (int off = 1; off < 256; off <<= 1) {
        int x = (threadIdx.x >= off) ? part[threadIdx.x - off] : 0;
        __syncthreads();
        part[threadIdx.x] += x;
        __syncthreads();
    }
    int run = bsum[blockIdx.x] + part[threadIdx.x] - s;
    if (idx0 + 3 < SN)
        *reinterpret_cast<int4*>(baseT + idx0) =
            make_int4(run, run + v.x, run + v.x + v.y, run + v.x + v.y + v.z);
}

// K3: scatter entries into per-(sorter,bucket) contiguous chunks
__global__ __launch_bounds__(256) void gc_sscat(
    const int2* __restrict__ edges, const float* __restrict__ wts,
    const int* __restrict__ baseT, int2* __restrict__ slab)
{
    __shared__ int cur[NB];
    const int s = blockIdx.x;
    for (int b = threadIdx.x; b < NB; b += 256) cur[b] = baseT[b * NS + s];
    __syncthreads();
    const int e0 = s * EPS;
    for (int i = threadIdx.x; i < EPS; i += 256) {
        int2 p = edges[e0 + i];
        int wb = __float_as_int(wts[e0 + i]);
        int b = p.y >> 7;
        int pos = atomicAdd(&cur[b], 1);
        slab[pos] = make_int2(p.x | ((p.y & 127) << 16), wb);
        b = p.x >> 7;
        pos = atomicAdd(&cur[b], 1);
        slab[pos] = make_int2(p.y | ((p.x & 127) << 16), wb);
    }
}

// K4: per-bucket CSR build from the contiguous bucket region
__global__ __launch_bounds__(256) void gc_csr(
    const int* __restrict__ baseT, const int2* __restrict__ slab,
    int* __restrict__ row_start, unsigned int* __restrict__ csr4)
{
    __shared__ int ncnt[128], ncur[128], part[128];
    const int tid = threadIdx.x;
    const int b = blockIdx.x;
    const int start = baseT[b * NS];
    const int end = (b == NB - 1) ? (2 * NE) : baseT[(b + 1) * NS];

    if (tid < 128) ncnt[tid] = 0;
    __syncthreads();

    for (int j = start + tid; j < end; j += 256)
        atomicAdd(&ncnt[(slab[j].x >> 16) & 127], 1);
    __syncthreads();

    if (tid < 128) part[tid] = ncnt[tid];
    __syncthreads();
    for (int off = 1; off < 128; off <<= 1) {
        int v = 0;
        if (tid < 128 && tid >= off) v = part[tid - off];
        __syncthreads();
        if (tid < 128) part[tid] += v;
        __syncthreads();
    }
    if (tid < 128) {
        int st = start + part[tid] - ncnt[tid];
        int n = b * 128 + tid;
        if (n < NN) row_start[n] = st;
        ncur[tid] = st;
    }
    if (b == 0 && tid == 0) row_start[NN] = 2 * NE;
    __syncthreads();

    for (int j = start + tid; j < end; j += 256) {
        int2 en = slab[j];
        int dl = (en.x >> 16) & 127;
        unsigned int hb =
            (unsigned int)__half_as_ushort(__float2half_rn(__int_as_float(en.y))) << 16;
        int pos = atomicAdd(&ncur[dl], 1);
        csr4[pos] = (unsigned int)(en.x & 0xffff) | hb;
    }
}

// K5: XW = X @ W, bf16 RNE, ROW-major output. 4x4 register blocking.
__global__ __launch_bounds__(256) void gc_gemm_rb(
    const float* __restrict__ src, unsigned short* __restrict__ dst,
    const float* __restrict__ Wm)
{
    __shared__ float Ws[D * D];        // 64 KB
    __shared__ float As[32 * D];       // 16 KB
    const int tid = threadIdx.x;
    const int tr  = tid >> 5;
    const int tc  = tid & 31;
    const int rbase = blockIdx.x * 32;

    const float4* W4  = reinterpret_cast<const float4*>(Wm);
    float4*       Ws4 = reinterpret_cast<float4*>(Ws);
    #pragma unroll
    for (int i = 0; i < 16; ++i) Ws4[tid + i * 256] = W4[tid + i * 256];

    const float4* X4  = reinterpret_cast<const float4*>(src);
    float4*       A4l = reinterpret_cast<float4*>(As);
    #pragma unroll
    for (int i = 0; i < 4; ++i) {
        int f = tid + i * 256;
        int r = f >> 5, q = f & 31;
        int grow = rbase + r;
        A4l[f] = (grow < NN) ? X4[(size_t)grow * 32 + q]
                             : make_float4(0.f, 0.f, 0.f, 0.f);
    }
    __syncthreads();

    float4 acc[4];
    #pragma unroll
    for (int i = 0; i < 4; ++i) acc[i] = make_float4(0.f, 0.f, 0.f, 0.f);

    for (int k4 = 0; k4 < 32; ++k4) {
        float4 w0 = Ws4[(4 * k4 + 0) * 32 + tc];
        float4 w1 = Ws4[(4 * k4 + 1) * 32 + tc];
        float4 w2 = Ws4[(4 * k4 + 2) * 32 + tc];
        float4 w3 = Ws4[(4 * k4 + 3) * 32 + tc];
        #pragma unroll
        for (int i = 0; i < 4; ++i) {
            float4 a = A4l[(tr * 4 + i) * 32 + k4];
            acc[i].x = fmaf(a.x, w0.x, acc[i].x); acc[i].y = fmaf(a.x, w0.y, acc[i].y);
            acc[i].z = fmaf(a.x, w0.z, acc[i].z); acc[i].w = fmaf(a.x, w0.w, acc[i].w);
            acc[i].x = fmaf(a.y, w1.x, acc[i].x); acc[i].y = fmaf(a.y, w1.y, acc[i].y);
            acc[i].z = fmaf(a.y, w1.z, acc[i].z); acc[i].w = fmaf(a.y, w1.w, acc[i].w);
            acc[i].x = fmaf(a.z, w2.x, acc[i].x); acc[i].y = fmaf(a.z, w2.y, acc[i].y);
            acc[i].z = fmaf(a.z, w2.z, acc[i].z); acc[i].w = fmaf(a.z, w2.w, acc[i].w);
            acc[i].x = fmaf(a.w, w3.x, acc[i].x); acc[i].y = fmaf(a.w, w3.y, acc[i].y);
            acc[i].z = fmaf(a.w, w3.z, acc[i].z); acc[i].w = fmaf(a.w, w3.w, acc[i].w);
        }
    }

    #pragma unroll
    for (int i = 0; i < 4; ++i) {
        int row = rbase + tr * 4 + i;
        if (row < NN) {
            ushort4 o;
            o.x = bf16rne(acc[i].x); o.y = bf16rne(acc[i].y);
            o.z = bf16rne(acc[i].z); o.w = bf16rne(acc[i].w);
            *reinterpret_cast<ushort4*>(dst + (size_t)row * D + tc * 4) = o;
        }
    }
}

// K6: gather bf16 rows (row-major), wave per node, 8x unroll for MLP depth.
__global__ __launch_bounds__(256) void gc_gather4(
    const int* __restrict__ row_start, const unsigned int* __restrict__ csr4,
    const unsigned int* __restrict__ F, float* __restrict__ out)
{
    int wid  = (blockIdx.x * 256 + threadIdx.x) >> 6;
    int lane = threadIdx.x & 63;
    if (wid >= NN) return;
    int j   = row_start[wid];
    int end = row_start[wid + 1];
    float ax = 0.f, ay = 0.f, dw = 0.f;
    for (; j + 8 <= end; j += 8) {
        unsigned int e0 = csr4[j],     e1 = csr4[j + 1];
        unsigned int e2 = csr4[j + 2], e3 = csr4[j + 3];
        unsigned int e4 = csr4[j + 4], e5 = csr4[j + 5];
        unsigned int e6 = csr4[j + 6], e7 = csr4[j + 7];
        unsigned int v0 = F[(size_t)(e0 & 0xffffu) * 64 + lane];
        unsigned int v1 = F[(size_t)(e1 & 0xffffu) * 64 + lane];
        unsigned int v2 = F[(size_t)(e2 & 0xffffu) * 64 + lane];
        unsigned int v3 = F[(size_t)(e3 & 0xffffu) * 64 + lane];
        unsigned int v4 = F[(size_t)(e4 & 0xffffu) * 64 + lane];
        unsigned int v5 = F[(size_t)(e5 & 0xffffu) * 64 + lane];
        unsigned int v6 = F[(size_t)(e6 & 0xffffu) * 64 + lane];
        unsigned int v7 = F[(size_t)(e7 & 0xffffu) * 64 + lane];
        float w0 = wdec(e0), w1 = wdec(e1), w2 = wdec(e2), w3 = wdec(e3);
        float w4 = wdec(e4), w5 = wdec(e5), w6 = wdec(e6), w7 = wdec(e7);
        ax = fmaf(w0, bf_lo(v0), ax); ay = fmaf(w0, bf_hi(v0), ay);
        ax = fmaf(w1, bf_lo(v1), ax); ay = fmaf(w1, bf_hi(v1), ay);
        ax = fmaf(w2, bf_lo(v2), ax); ay = fmaf(w2, bf_hi(v2), ay);
        ax = fmaf(w3, bf_lo(v3), ax); ay = fmaf(w3, bf_hi(v3), ay);
        ax = fmaf(w4, bf_lo(v4), ax); ay = fmaf(w4, bf_hi(v4), ay);
        ax = fmaf(w5, bf_lo(v5), ax); ay = fmaf(w5, bf_hi(v5), ay);
        ax = fmaf(w6, bf_lo(v6), ax); ay = fmaf(w6, bf_hi(v6), ay);
        ax = fmaf(w7, bf_lo(v7), ax); ay = fmaf(w7, bf_hi(v7), ay);
        dw += (w0 + w1 + w2 + w3) + (w4 + w5 + w6 + w7);
    }
    for (; j < end; ++j) {
        unsigned int e0 = csr4[j];
        unsigned int v0 = F[(size_t)(e0 & 0xffffu) * 64 + lane];
        float w0 = wdec(e0);
        ax = fmaf(w0, bf_lo(v0), ax); ay = fmaf(w0, bf_hi(v0), ay);
        dw += w0;
    }
    float inv = dw > 0.f ? 1.f / dw : 0.f;
    float2 r; r.x = ax * inv; r.y = ay * inv;
    reinterpret_cast<float2*>(out)[(size_t)wid * 64 + lane] = r;
}

// ======================= fallback path (fp32, small ws) ====================
__global__ __launch_bounds__(256) void gc_hist(
    const int2* __restrict__ edges, int* __restrict__ counts)
{
    int e = blockIdx.x * 256 + threadIdx.x;
    if (e >= NE) return;
    int2 p = edges[e];
    atomicAdd(counts + p.x, 1);
    atomicAdd(counts + p.y, 1);
}

__global__ __launch_bounds__(1024) void gc_scan(
    const int* __restrict__ counts, int* __restrict__ row_start,
    int* __restrict__ cursor)
{
    const int CHUNK = (NN + 1023) / 1024;
    __shared__ int part[1024];
    int t = threadIdx.x;
    int lo = t * CHUNK, hi = min(lo + CHUNK, NN);
    int s = 0;
    for (int i = lo; i < hi; ++i) s += counts[i];
    part[t] = s;
    __syncthreads();
    for (int off = 1; off < 1024; off <<= 1) {
        int v = (t >= off) ? part[t - off] : 0;
        __syncthreads();
        part[t] += v;
        __syncthreads();
    }
    int run = part[t] - s;
    for (int i = lo; i < hi; ++i) {
        int c = counts[i];
        row_start[i] = run;
        cursor[i]    = run;
        run += c;
    }
    if (t == 1023) row_start[NN] = part[1023];
}

__global__ __launch_bounds__(256) void gc_fill8(
    const int2* __restrict__ edges, const float* __restrict__ wts,
    int* __restrict__ cursor, int2* __restrict__ csr)
{
    int e = blockIdx.x * 256 + threadIdx.x;
    if (e >= NE) return;
    int2 p = edges[e];
    int wb = __float_as_int(wts[e]);
    int pos = atomicAdd(cursor + p.y, 1);
    csr[pos] = make_int2(p.x, wb);
    pos = atomicAdd(cursor + p.x, 1);
    csr[pos] = make_int2(p.y, wb);
}

__global__ __launch_bounds__(256) void gc_gather_f32(
    const int* __restrict__ row_start, const int2* __restrict__ csr,
    const float* __restrict__ F, float* __restrict__ out)
{
    int wid  = (blockIdx.x * 256 + threadIdx.x) >> 6;
    int lane = threadIdx.x & 63;
    if (wid >= NN) return;
    int j   = row_start[wid];
    int end = row_start[wid + 1];
    const float2* F2 = reinterpret_cast<const float2*>(F);
    float ax = 0.f, ay = 0.f, dw = 0.f;
    for (; j < end; ++j) {
        int2  cw = csr[j];
        float w  = __int_as_float(cw.y);
        float2 xv = F2[(size_t)cw.x * 64 + lane];
        ax = fmaf(w, xv.x, ax);
        ay = fmaf(w, xv.y, ay);
        dw += w;
    }
    float inv = dw > 0.f ? 1.f / dw : 0.f;
    float2 r; r.x = ax * inv; r.y = ay * inv;
    reinterpret_cast<float2*>(out)[(size_t)wid * 64 + lane] = r;
}

__global__ __launch_bounds__(256) void gc_gemm_f32(
    const float* __restrict__ src, float* __restrict__ dst,
    const float* __restrict__ Wm)
{
    __shared__ float Ws[D * D];
    __shared__ float axs[16 * D];
    const int tid = threadIdx.x;
    const int col = tid & 127;
    const int ty  = tid >> 7;
    const int rbase = blockIdx.x * 16;

    const float4* W4  = reinterpret_cast<const float4*>(Wm);
    float4*       Ws4 = reinterpret_cast<float4*>(Ws);
    #pragma unroll
    for (int i = 0; i < 16; ++i) Ws4[tid + i * 256] = W4[tid + i * 256];

    const float4* A4   = reinterpret_cast<const float4*>(src + (size_t)rbase * D);
    float4*       axs4 = reinterpret_cast<float4*>(axs);
    #pragma unroll
    for (int i = 0; i < 2; ++i) axs4[tid + i * 256] = A4[tid + i * 256];
    __syncthreads();

    float acc[8];
    #pragma unroll
    for (int i = 0; i < 8; ++i) acc[i] = 0.f;

    for (int k = 0; k < D; ++k) {
        float wv = Ws[k * D + col];
        #pragma unroll
        for (int i = 0; i < 8; ++i)
            acc[i] = fmaf(axs[(ty * 8 + i) * D + k], wv, acc[i]);
    }

    #pragma unroll
    for (int i = 0; i < 8; ++i)
        dst[(size_t)(rbase + ty * 8 + i) * D + col] = acc[i];
}

extern "C" void kernel_launch(void* const* d_in, const int* in_sizes, int n_in,
                              void* d_out, int out_size, void* d_ws, size_t ws_size,
                              hipStream_t stream) {
    const float* X     = (const float*)d_in[0];
    const int2*  edges = (const int2*)d_in[1];
    const float* wts   = (const float*)d_in[2];
    const float* Wm    = (const float*)d_in[3];
    float* out = (float*)d_out;
    char*  ws  = (char*)d_ws;

    const int eblocks = (NE + 255) / 256;

    if (ws_size >= NEED_A) {
        int2* slab  = (int2*)(ws + OFF_SLAB);
        unsigned int* csr4 = (unsigned int*)(ws + OFF_CSR4);
        int*  histT = (int*)(ws + OFF_HIST);
        int*  baseT = (int*)(ws + OFF_BASE);
        int*  bsum  = (int*)(ws + OFF_BSUM);
        int*  row   = (int*)(ws + OFF_ROW);
        unsigned short* xw = (unsigned short*)(ws + OFF_XW);   // aliases dead slab

        gc_shist<<<NS, 256, 0, stream>>>(edges, histT);
        gc_scanA<<<NSB, 256, 0, stream>>>(histT, bsum);
        gc_scanB<<<1, 1024, 0, stream>>>(bsum);
        gc_scanC<<<NSB, 256, 0, stream>>>(histT, bsum, baseT);
        gc_sscat<<<NS, 256, 0, stream>>>(edges, wts, baseT, slab);
        gc_csr<<<NB, 256, 0, stream>>>(baseT, slab, row, csr4);
        gc_gemm_rb<<<(NN + 31) / 32, 256, 0, stream>>>(X, xw, Wm);  // overwrites slab
        gc_gather4<<<(NN * 64 + 255) / 256, 256, 0, stream>>>(
            row, csr4, (const unsigned int*)xw, out);
    } else {
        int*  counts    = (int*) (ws + OFF_CNT);
        int*  row_start = (int*) (ws + OFF_ROWF);
        int*  cursor    = (int*) (ws + OFF_CUR);
        int2* csr       = (int2*)(ws + OFF_CSR8);

        hipMemsetAsync(counts, 0, NN * sizeof(int), stream);
        gc_hist<<<eblocks, 256, 0, stream>>>(edges, counts);
        gc_scan<<<1, 1024, 0, stream>>>(counts, row_start, cursor);
        gc_fill8<<<eblocks, 256, 0, stream>>>(edges, wts, cursor, csr);
        gc_gather_f32<<<(NN * 64 + 255) / 256, 256, 0, stream>>>(row_start, csr, X, out);
        gc_gemm_f32<<<NN / 16, 256, 0, stream>>>(out, out, Wm);
    }
}

// Round 15
// 114.286 us; speedup vs baseline: 1.4389x; 1.1399x over previous
//
#include <hip/hip_runtime.h>
#include <hip/hip_fp16.h>

#define NN 50000
#define NE 800000
#define D  128
#define NB 391                 // node buckets of 128
#define NS 256                 // sorter blocks
#define EPS 3125               // edges per sorter (NS*EPS == NE)
#define SN (NB * NS)           // 100096 scan elements
#define SCB 1024
#define NSB ((SN + SCB - 1) / SCB)   // 98

// ---- main-path ws layout (bytes) ----
#define OFF_SLAB 0             // int2[2E]      12,800,000
#define OFF_XW   0             // ushort[NN*D]  12,800,000 (row-major; aliases dead slab)
#define OFF_CSR4 12800000      // uint[2E]       6,400,000
#define OFF_HIST 19200000      // int[SN]          400,384
#define OFF_BASE 19600384      // int[SN]          400,384
#define OFF_BSUM 20000768      // int[NSB]             512
#define OFF_ROW  20001280      // int[NN+1]        200,004
#define OFF_WF   20201344      // ushort[128*128]   32,768 (W bf16 fragments)
#define NEED_A   20234112

// ---- fallback ws layout ----
#define OFF_CNT  0
#define OFF_ROWF 200704
#define OFF_CUR  401408
#define OFF_CSR8 602112

typedef float v2f  __attribute__((ext_vector_type(2)));
typedef __attribute__((ext_vector_type(8))) short bf16x8;
typedef __attribute__((ext_vector_type(4))) float f32x4;

__device__ __forceinline__ float bf_lo(unsigned int v) { return __uint_as_float(v << 16); }
__device__ __forceinline__ float bf_hi(unsigned int v) { return __uint_as_float(v & 0xffff0000u); }
__device__ __forceinline__ float wdec(unsigned int v) {
    return __half2float(__ushort_as_half((unsigned short)(v >> 16)));
}
__device__ __forceinline__ unsigned short bf16rne(float f) {
    unsigned int b = __float_as_uint(f);
    return (unsigned short)((b + 0x7fffu + ((b >> 16) & 1u)) >> 16);
}

// K1: per-sorter histogram over 391 buckets (LDS), b-major output
__global__ __launch_bounds__(256) void gc_shist(
    const int2* __restrict__ edges, int* __restrict__ histT)
{
    __shared__ int h[NB];
    const int s = blockIdx.x;
    for (int i = threadIdx.x; i < NB; i += 256) h[i] = 0;
    __syncthreads();
    const int e0 = s * EPS;
    for (int i = threadIdx.x; i < EPS; i += 256) {
        int2 p = edges[e0 + i];
        atomicAdd(&h[p.y >> 7], 1);
        atomicAdd(&h[p.x >> 7], 1);
    }
    __syncthreads();
    for (int b = threadIdx.x; b < NB; b += 256) histT[b * NS + s] = h[b];
}

// K2a/b/c: hierarchical exclusive scan over SN elements
__global__ __launch_bounds__(256) void gc_scanA(
    const int* __restrict__ in, int* __restrict__ bsum)
{
    __shared__ int red[256];
    int base = blockIdx.x * SCB;
    int s = 0;
    for (int i = threadIdx.x; i < SCB; i += 256) {
        int idx = base + i;
        s += (idx < SN) ? in[idx] : 0;
    }
    red[threadIdx.x] = s;
    __syncthreads();
    for (int off = 128; off > 0; off >>= 1) {
        if (threadIdx.x < off) red[threadIdx.x] += red[threadIdx.x + off];
        __syncthreads();
    }
    if (threadIdx.x == 0) bsum[blockIdx.x] = red[0];
}

__global__ __launch_bounds__(1024) void gc_scanB(int* __restrict__ bsum)
{
    __shared__ int part[1024];
    int t = threadIdx.x;
    int v = (t < NSB) ? bsum[t] : 0;
    part[t] = v;
    __syncthreads();
    for (int off = 1; off < 1024; off <<= 1) {
        int x = (t >= off) ? part[t - off] : 0;
        __syncthreads();
        part[t] += x;
        __syncthreads();
    }
    if (t < NSB) bsum[t] = part[t] - v;
}

__global__ __launch_bounds__(256) void gc_scanC(
    const int* __restrict__ in, const int* __restrict__ bsum,
    int* __restrict__ baseT)
{
    __shared__ int part[256];
    int base = blockIdx.x * SCB;
    int idx0 = base + threadIdx.x * 4;
    int4 v = make_int4(0, 0, 0, 0);
    if (idx0 + 3 < SN) v = *reinterpret_cast<const int4*>(in + idx0);
    int s = v.x + v.y + v.z + v.w;
    part[threadIdx.x] = s;
    __syncthreads();
    for (int off = 1; off < 256; off <<= 1) {
        int x = (threadIdx.x >= off) ? part[threadIdx.x - off] : 0;
        __syncthreads();
        part[threadIdx.x] += x;
        __syncthreads();
    }
    int run = bsum[blockIdx.x] + part[threadIdx.x] - s;
    if (idx0 + 3 < SN)
        *reinterpret_cast<int4*>(baseT + idx0) =
            make_int4(run, run + v.x, run + v.x + v.y, run + v.x + v.y + v.z);
}

// K3: scatter entries into per-(sorter,bucket) contiguous chunks
__global__ __launch_bounds__(256) void gc_sscat(
    const int2* __restrict__ edges, const float* __restrict__ wts,
    const int* __restrict__ baseT, int2* __restrict__ slab)
{
    __shared__ int cur[NB];
    const int s = blockIdx.x;
    for (int b = threadIdx.x; b < NB; b += 256) cur[b] = baseT[b * NS + s];
    __syncthreads();
    const int e0 = s * EPS;
    for (int i = threadIdx.x; i < EPS; i += 256) {
        int2 p = edges[e0 + i];
        int wb = __float_as_int(wts[e0 + i]);
        int b = p.y >> 7;
        int pos = atomicAdd(&cur[b], 1);
        slab[pos] = make_int2(p.x | ((p.y & 127) << 16), wb);
        b = p.x >> 7;
        pos = atomicAdd(&cur[b], 1);
        slab[pos] = make_int2(p.y | ((p.x & 127) << 16), wb);
    }
}

// K4: per-bucket CSR build from the contiguous bucket region
__global__ __launch_bounds__(256) void gc_csr(
    const int* __restrict__ baseT, const int2* __restrict__ slab,
    int* __restrict__ row_start, unsigned int* __restrict__ csr4)
{
    __shared__ int ncnt[128], ncur[128], part[128];
    const int tid = threadIdx.x;
    const int b = blockIdx.x;
    const int start = baseT[b * NS];
    const int end = (b == NB - 1) ? (2 * NE) : baseT[(b + 1) * NS];

    if (tid < 128) ncnt[tid] = 0;
    __syncthreads();

    for (int j = start + tid; j < end; j += 256)
        atomicAdd(&ncnt[(slab[j].x >> 16) & 127], 1);
    __syncthreads();

    if (tid < 128) part[tid] = ncnt[tid];
    __syncthreads();
    for (int off = 1; off < 128; off <<= 1) {
        int v = 0;
        if (tid < 128 && tid >= off) v = part[tid - off];
        __syncthreads();
        if (tid < 128) part[tid] += v;
        __syncthreads();
    }
    if (tid < 128) {
        int st = start + part[tid] - ncnt[tid];
        int n = b * 128 + tid;
        if (n < NN) row_start[n] = st;
        ncur[tid] = st;
    }
    if (b == 0 && tid == 0) row_start[NN] = 2 * NE;
    __syncthreads();

    for (int j = start + tid; j < end; j += 256) {
        int2 en = slab[j];
        int dl = (en.x >> 16) & 127;
        unsigned int hb =
            (unsigned int)__half_as_ushort(__float2half_rn(__int_as_float(en.y))) << 16;
        int pos = atomicAdd(&ncur[dl], 1);
        csr4[pos] = (unsigned int)(en.x & 0xffff) | hb;
    }
}

// K5a: pack W (fp32 row-major [k][n]) into MFMA B-fragment order, bf16.
// wf[((ki*8 + nt)*64 + lane)*8 + j] = bf16(W[ki*32 + (lane>>4)*8 + j][nt*16 + (lane&15)])
__global__ __launch_bounds__(256) void gc_wfrag(
    const float* __restrict__ Wm, unsigned short* __restrict__ wf)
{
    int t = blockIdx.x * 256 + threadIdx.x;      // 16384 total
    int j    = t & 7;
    int lane = (t >> 3) & 63;
    int nt   = (t >> 9) & 7;
    int ki   = t >> 12;
    int k = ki * 32 + (lane >> 4) * 8 + j;
    int n = nt * 16 + (lane & 15);
    wf[t] = bf16rne(Wm[k * D + n]);
}

// K5b: XW = X @ W via MFMA 16x16x32 bf16. 4 waves/block, 16 rows/wave.
// A frag: row = lane&15, k = ki*32 + (lane>>4)*8 + j (converted from fp32 X).
// C/D: col = lane&15, row = (lane>>4)*4 + reg.
__global__ __launch_bounds__(256) void gc_gemm_mfma(
    const float* __restrict__ X, const unsigned short* __restrict__ wf,
    unsigned short* __restrict__ dst)
{
    const int lane = threadIdx.x & 63;
    const int wave = threadIdx.x >> 6;
    const int rbase = blockIdx.x * 64 + wave * 16;
    const int r  = lane & 15;
    const int kb = lane >> 4;

    f32x4 acc[8];
    #pragma unroll
    for (int i = 0; i < 8; ++i) acc[i] = f32x4{0.f, 0.f, 0.f, 0.f};

    const bf16x8* wfv = reinterpret_cast<const bf16x8*>(wf);
    const int row = rbase + r;
    const bool rok = row < NN;

    #pragma unroll
    for (int ki = 0; ki < 4; ++ki) {
        float4 a0 = make_float4(0.f, 0.f, 0.f, 0.f);
        float4 a1 = make_float4(0.f, 0.f, 0.f, 0.f);
        if (rok) {
            const float4* xp = reinterpret_cast<const float4*>(
                X + (size_t)row * D + ki * 32 + kb * 8);
            a0 = xp[0];
            a1 = xp[1];
        }
        bf16x8 af;
        af[0] = (short)bf16rne(a0.x); af[1] = (short)bf16rne(a0.y);
        af[2] = (short)bf16rne(a0.z); af[3] = (short)bf16rne(a0.w);
        af[4] = (short)bf16rne(a1.x); af[5] = (short)bf16rne(a1.y);
        af[6] = (short)bf16rne(a1.z); af[7] = (short)bf16rne(a1.w);
        #pragma unroll
        for (int nt = 0; nt < 8; ++nt) {
            bf16x8 bf = wfv[(ki * 8 + nt) * 64 + lane];
            acc[nt] = __builtin_amdgcn_mfma_f32_16x16x32_bf16(af, bf, acc[nt], 0, 0, 0);
        }
    }

    const int orow0 = rbase + kb * 4;
    #pragma unroll
    for (int nt = 0; nt < 8; ++nt) {
        #pragma unroll
        for (int reg = 0; reg < 4; ++reg) {
            int orow = orow0 + reg;
            if (orow < NN)
                dst[(size_t)orow * D + nt * 16 + r] = bf16rne(acc[nt][reg]);
        }
    }
}

// K6: gather bf16 rows, wave per node, 8x unroll, 32-bit addressing,
// packed-f32 accumulation.
__global__ __launch_bounds__(256) void gc_gather4(
    const int* __restrict__ row_start, const unsigned int* __restrict__ csr4,
    const unsigned int* __restrict__ F, float* __restrict__ out)
{
    int wid  = (blockIdx.x * 256 + threadIdx.x) >> 6;
    unsigned int lane = threadIdx.x & 63;
    if (wid >= NN) return;
    int j   = row_start[wid];
    int end = row_start[wid + 1];
    v2f acc = {0.f, 0.f};
    float dw = 0.f;
    for (; j + 8 <= end; j += 8) {
        unsigned int e0 = csr4[j],     e1 = csr4[j + 1];
        unsigned int e2 = csr4[j + 2], e3 = csr4[j + 3];
        unsigned int e4 = csr4[j + 4], e5 = csr4[j + 5];
        unsigned int e6 = csr4[j + 6], e7 = csr4[j + 7];
        unsigned int v0 = F[((e0 & 0xffffu) << 6) | lane];
        unsigned int v1 = F[((e1 & 0xffffu) << 6) | lane];
        unsigned int v2 = F[((e2 & 0xffffu) << 6) | lane];
        unsigned int v3 = F[((e3 & 0xffffu) << 6) | lane];
        unsigned int v4 = F[((e4 & 0xffffu) << 6) | lane];
        unsigned int v5 = F[((e5 & 0xffffu) << 6) | lane];
        unsigned int v6 = F[((e6 & 0xffffu) << 6) | lane];
        unsigned int v7 = F[((e7 & 0xffffu) << 6) | lane];
        float w0 = wdec(e0), w1 = wdec(e1), w2 = wdec(e2), w3 = wdec(e3);
        float w4 = wdec(e4), w5 = wdec(e5), w6 = wdec(e6), w7 = wdec(e7);
        acc += w0 * v2f{bf_lo(v0), bf_hi(v0)};
        acc += w1 * v2f{bf_lo(v1), bf_hi(v1)};
        acc += w2 * v2f{bf_lo(v2), bf_hi(v2)};
        acc += w3 * v2f{bf_lo(v3), bf_hi(v3)};
        acc += w4 * v2f{bf_lo(v4), bf_hi(v4)};
        acc += w5 * v2f{bf_lo(v5), bf_hi(v5)};
        acc += w6 * v2f{bf_lo(v6), bf_hi(v6)};
        acc += w7 * v2f{bf_lo(v7), bf_hi(v7)};
        dw += (w0 + w1 + w2 + w3) + (w4 + w5 + w6 + w7);
    }
    for (; j < end; ++j) {
        unsigned int e0 = csr4[j];
        unsigned int v0 = F[((e0 & 0xffffu) << 6) | lane];
        float w0 = wdec(e0);
        acc += w0 * v2f{bf_lo(v0), bf_hi(v0)};
        dw += w0;
    }
    float inv = dw > 0.f ? 1.f / dw : 0.f;
    float2 r; r.x = acc.x * inv; r.y = acc.y * inv;
    reinterpret_cast<float2*>(out)[(size_t)wid * 64 + lane] = r;
}

// ======================= fallback path (fp32, small ws) ====================
__global__ __launch_bounds__(256) void gc_hist(
    const int2* __restrict__ edges, int* __restrict__ counts)
{
    int e = blockIdx.x * 256 + threadIdx.x;
    if (e >= NE) return;
    int2 p = edges[e];
    atomicAdd(counts + p.x, 1);
    atomicAdd(counts + p.y, 1);
}

__global__ __launch_bounds__(1024) void gc_scan(
    const int* __restrict__ counts, int* __restrict__ row_start,
    int* __restrict__ cursor)
{
    const int CHUNK = (NN + 1023) / 1024;
    __shared__ int part[1024];
    int t = threadIdx.x;
    int lo = t * CHUNK, hi = min(lo + CHUNK, NN);
    int s = 0;
    for (int i = lo; i < hi; ++i) s += counts[i];
    part[t] = s;
    __syncthreads();
    for (int off = 1; off < 1024; off <<= 1) {
        int v = (t >= off) ? part[t - off] : 0;
        __syncthreads();
        part[t] += v;
        __syncthreads();
    }
    int run = part[t] - s;
    for (int i = lo; i < hi; ++i) {
        int c = counts[i];
        row_start[i] = run;
        cursor[i]    = run;
        run += c;
    }
    if (t == 1023) row_start[NN] = part[1023];
}

__global__ __launch_bounds__(256) void gc_fill8(
    const int2* __restrict__ edges, const float* __restrict__ wts,
    int* __restrict__ cursor, int2* __restrict__ csr)
{
    int e = blockIdx.x * 256 + threadIdx.x;
    if (e >= NE) return;
    int2 p = edges[e];
    int wb = __float_as_int(wts[e]);
    int pos = atomicAdd(cursor + p.y, 1);
    csr[pos] = make_int2(p.x, wb);
    pos = atomicAdd(cursor + p.x, 1);
    csr[pos] = make_int2(p.y, wb);
}

__global__ __launch_bounds__(256) void gc_gather_f32(
    const int* __restrict__ row_start, const int2* __restrict__ csr,
    const float* __restrict__ F, float* __restrict__ out)
{
    int wid  = (blockIdx.x * 256 + threadIdx.x) >> 6;
    int lane = threadIdx.x & 63;
    if (wid >= NN) return;
    int j   = row_start[wid];
    int end = row_start[wid + 1];
    const float2* F2 = reinterpret_cast<const float2*>(F);
    float ax = 0.f, ay = 0.f, dw = 0.f;
    for (; j < end; ++j) {
        int2  cw = csr[j];
        float w  = __int_as_float(cw.y);
        float2 xv = F2[(size_t)cw.x * 64 + lane];
        ax = fmaf(w, xv.x, ax);
        ay = fmaf(w, xv.y, ay);
        dw += w;
    }
    float inv = dw > 0.f ? 1.f / dw : 0.f;
    float2 r; r.x = ax * inv; r.y = ay * inv;
    reinterpret_cast<float2*>(out)[(size_t)wid * 64 + lane] = r;
}

__global__ __launch_bounds__(256) void gc_gemm_f32(
    const float* __restrict__ src, float* __restrict__ dst,
    const float* __restrict__ Wm)
{
    __shared__ float Ws[D * D];
    __shared__ float axs[16 * D];
    const int tid = threadIdx.x;
    const int col = tid & 127;
    const int ty  = tid >> 7;
    const int rbase = blockIdx.x * 16;

    const float4* W4  = reinterpret_cast<const float4*>(Wm);
    float4*       Ws4 = reinterpret_cast<float4*>(Ws);
    #pragma unroll
    for (int i = 0; i < 16; ++i) Ws4[tid + i * 256] = W4[tid + i * 256];

    const float4* A4   = reinterpret_cast<const float4*>(src + (size_t)rbase * D);
    float4*       axs4 = reinterpret_cast<float4*>(axs);
    #pragma unroll
    for (int i = 0; i < 2; ++i) axs4[tid + i * 256] = A4[tid + i * 256];
    __syncthreads();

    float acc[8];
    #pragma unroll
    for (int i = 0; i < 8; ++i) acc[i] = 0.f;

    for (int k = 0; k < D; ++k) {
        float wv = Ws[k * D + col];
        #pragma unroll
        for (int i = 0; i < 8; ++i)
            acc[i] = fmaf(axs[(ty * 8 + i) * D + k], wv, acc[i]);
    }

    #pragma unroll
    for (int i = 0; i < 8; ++i)
        dst[(size_t)(rbase + ty * 8 + i) * D + col] = acc[i];
}

extern "C" void kernel_launch(void* const* d_in, const int* in_sizes, int n_in,
                              void* d_out, int out_size, void* d_ws, size_t ws_size,
                              hipStream_t stream) {
    const float* X     = (const float*)d_in[0];
    const int2*  edges = (const int2*)d_in[1];
    const float* wts   = (const float*)d_in[2];
    const float* Wm    = (const float*)d_in[3];
    float* out = (float*)d_out;
    char*  ws  = (char*)d_ws;

    const int eblocks = (NE + 255) / 256;

    if (ws_size >= NEED_A) {
        int2* slab  = (int2*)(ws + OFF_SLAB);
        unsigned int* csr4 = (unsigned int*)(ws + OFF_CSR4);
        int*  histT = (int*)(ws + OFF_HIST);
        int*  baseT = (int*)(ws + OFF_BASE);
        int*  bsum  = (int*)(ws + OFF_BSUM);
        int*  row   = (int*)(ws + OFF_ROW);
        unsigned short* wf = (unsigned short*)(ws + OFF_WF);
        unsigned short* xw = (unsigned short*)(ws + OFF_XW);   // aliases dead slab

        gc_shist<<<NS, 256, 0, stream>>>(edges, histT);
        gc_scanA<<<NSB, 256, 0, stream>>>(histT, bsum);
        gc_scanB<<<1, 1024, 0, stream>>>(bsum);
        gc_scanC<<<NSB, 256, 0, stream>>>(histT, bsum, baseT);
        gc_sscat<<<NS, 256, 0, stream>>>(edges, wts, baseT, slab);
        gc_wfrag<<<64, 256, 0, stream>>>(Wm, wf);
        gc_csr<<<NB, 256, 0, stream>>>(baseT, slab, row, csr4);
        gc_gemm_mfma<<<(NN + 63) / 64, 256, 0, stream>>>(X, wf, xw);  // overwrites slab
        gc_gather4<<<(NN * 64 + 255) / 256, 256, 0, stream>>>(
            row, csr4, (const unsigned int*)xw, out);
    } else {
        int*  counts    = (int*) (ws + OFF_CNT);
        int*  row_start = (int*) (ws + OFF_ROWF);
        int*  cursor    = (int*) (ws + OFF_CUR);
        int2* csr       = (int2*)(ws + OFF_CSR8);

        hipMemsetAsync(counts, 0, NN * sizeof(int), stream);
        gc_hist<<<eblocks, 256, 0, stream>>>(edges, counts);
        gc_scan<<<1, 1024, 0, stream>>>(counts, row_start, cursor);
        gc_fill8<<<eblocks, 256, 0, stream>>>(edges, wts, cursor, csr);
        gc_gather_f32<<<(NN * 64 + 255) / 256, 256, 0, stream>>>(row_start, csr, X, out);
        gc_gemm_f32<<<NN / 16, 256, 0, stream>>>(out, out, Wm);
    }
}